// Round 5
// baseline (161.887 us; speedup 1.0000x reference)
//
#include <hip/hip_runtime.h>
#include <math.h>

// Problem constants (shapes fixed by setup_inputs)
#define B     4
#define DIM   256
#define NP    128   // nPnt
#define NS    144   // 12*12 unique token_init rows per batch
#define HID   512   // 4*nPnt
#define NROW  576   // B*NS
#define H_OUT 120
#define W_OUT 160

// Tanh-form GELU: x * sigmoid(1.595769122x(1+0.044715x^2)), computed
// NaN-safe as x*(1 - 1/(e+1)), e = exp2(x*(c1 + c2*x^2)).
// |err vs exact-erf gelu| < ~3e-4 abs; output tolerance is 8.6e-2.
__device__ __forceinline__ float gelu_fast(float x) {
    const float x2 = x * x;
    const float u  = x * (2.302052793f + 0.10293626f * x2);
    const float e  = exp2f(u);
    const float r  = __builtin_amdgcn_rcpf(e + 1.0f);
    return x - x * r;
}

// ---------------------------------------------------------------------------
// K_mlp: fused Q -> layer1 -> layer2 (-> softmax) for BOTH MLPs.
// One block = one (mlp, 4-row tile). grid = 2*144 + 1 = 289 blocks.
// Block 288 precomputes folded tf-MLP layer-1 weights w1p[24][48] for k_fold.
// Stage A reads point_token row-major directly (no transpose kernel): thread
// = (p, d-half); 16B/lane scatter is L1-absorbed (each 128B line fully
// consumed by the same thread's next iterations) -> L2 traffic = panel once.
// Stage B: thread owns k-pair, all 4 rows -> w1 streamed exactly once.
// ---------------------------------------------------------------------------
__global__ __launch_bounds__(256) void k_mlp(
    const float* __restrict__ ti, const float* __restrict__ pt,
    const float* __restrict__ nr_w1, const float* __restrict__ nr_b1,
    const float* __restrict__ nr_w2, const float* __restrict__ nr_b2,
    const float* __restrict__ na_w1, const float* __restrict__ na_b1,
    const float* __restrict__ na_w2, const float* __restrict__ na_b2,
    const float* __restrict__ tf_w1,
    float* __restrict__ nadjT, float* __restrict__ attn,
    float* __restrict__ w1pg)
{
    const int t = threadIdx.x;

    if (blockIdx.x == 288) {   // fold tf_w1 pairs: w1p[m][k] = w1[2m][k]+w1[2m+1][k]
        for (int i = t; i < 24 * 48; i += 256) {
            const int m = i / 48, k = i - m * 48;
            w1pg[i] = tf_w1[(2 * m) * 48 + k] + tf_w1[(2 * m + 1) * 48 + k];
        }
        return;
    }

    const int mlp  = blockIdx.x / 144;
    const int tile = blockIdx.x % 144;
    const int g0 = tile * 4;        // 4 consecutive rows, never crosses batch
    const int b  = g0 / NS;
    const int n0 = g0 % NS;

    const float* __restrict__ w1 = mlp ? na_w1 : nr_w1;
    const float* __restrict__ b1 = mlp ? na_b1 : nr_b1;
    const float* __restrict__ w2 = mlp ? na_w2 : nr_w2;
    const float* __restrict__ b2 = mlp ? na_b2 : nr_b2;

    __shared__ float xs[4][DIM];        //  4 KB  ti rows
    __shared__ float qsT[NP][4];        //  2 KB  Q transposed (p-major)
    __shared__ float hs[4][HID];        //  8 KB
    __shared__ float par[8][4][NP];     // 16 KB  layer-2 partials
    __shared__ float wred[4][2];        // softmax wave-exchange scratch

    // ---- Stage A: Q[4][128] = ti_rows @ pt^T, direct row-major reads ------
    {
        const int r = t >> 6, c = t & 63;
        ((float4*)xs[r])[c] = ((const float4*)ti)[(size_t)(g0 + r) * 64 + c];
    }
    __syncthreads();

    {
        const int p  = t >> 1;          // 0..127
        const int dh = t & 1;           // d-half (128 d's each)
        const float4* __restrict__ pt4 =
            (const float4*)(pt + (size_t)(b * NP + p) * DIM) + dh * 32;
        const float4* __restrict__ x0p = (const float4*)xs[0] + dh * 32;
        const float4* __restrict__ x1p = (const float4*)xs[1] + dh * 32;
        const float4* __restrict__ x2p = (const float4*)xs[2] + dh * 32;
        const float4* __restrict__ x3p = (const float4*)xs[3] + dh * 32;
        float4 a0 = make_float4(0.f,0.f,0.f,0.f);
        float4 a1 = a0, a2 = a0, a3 = a0;
        #pragma unroll 8
        for (int i = 0; i < 32; ++i) {
            const float4 pv = pt4[i];
            const float4 x0 = x0p[i], x1 = x1p[i];
            const float4 x2 = x2p[i], x3 = x3p[i];
            a0.x += x0.x*pv.x; a0.y += x0.y*pv.y; a0.z += x0.z*pv.z; a0.w += x0.w*pv.w;
            a1.x += x1.x*pv.x; a1.y += x1.y*pv.y; a1.z += x1.z*pv.z; a1.w += x1.w*pv.w;
            a2.x += x2.x*pv.x; a2.y += x2.y*pv.y; a2.z += x2.z*pv.z; a2.w += x2.w*pv.w;
            a3.x += x3.x*pv.x; a3.y += x3.y*pv.y; a3.z += x3.z*pv.z; a3.w += x3.w*pv.w;
        }
        float s0 = (a0.x + a0.y) + (a0.z + a0.w);
        float s1 = (a1.x + a1.y) + (a1.z + a1.w);
        float s2 = (a2.x + a2.y) + (a2.z + a2.w);
        float s3 = (a3.x + a3.y) + (a3.z + a3.w);
        s0 += __shfl_xor(s0, 1);
        s1 += __shfl_xor(s1, 1);
        s2 += __shfl_xor(s2, 1);
        s3 += __shfl_xor(s3, 1);
        if (dh == 0) {
            qsT[p][0] = s0 * 0.0625f;
            qsT[p][1] = s1 * 0.0625f;
            qsT[p][2] = s2 * 0.0625f;
            qsT[p][3] = s3 * 0.0625f;
        }
    }
    __syncthreads();

    // ---- Stage B: H = gelu(b1 + Q @ w1); w1 streamed exactly once ---------
    {
        const int k0 = 2 * t;           // k-pair; 256 threads cover all 512 k
        const float2 bv = *(const float2*)(b1 + k0);
        float2 a0 = bv, a1 = bv, a2 = bv, a3 = bv;
        const float* __restrict__ wp = w1 + k0;
        #pragma unroll 16
        for (int pp = 0; pp < NP; ++pp) {
            const float2 wv = *(const float2*)(wp + (size_t)pp * HID);
            const float4 q  = *(const float4*)qsT[pp];   // broadcast b128
            a0.x += q.x*wv.x; a0.y += q.x*wv.y;
            a1.x += q.y*wv.x; a1.y += q.y*wv.y;
            a2.x += q.z*wv.x; a2.y += q.z*wv.y;
            a3.x += q.w*wv.x; a3.y += q.w*wv.y;
        }
        float2 o;
        o.x = gelu_fast(a0.x); o.y = gelu_fast(a0.y);
        *(float2*)(&hs[0][k0]) = o;
        o.x = gelu_fast(a1.x); o.y = gelu_fast(a1.y);
        *(float2*)(&hs[1][k0]) = o;
        o.x = gelu_fast(a2.x); o.y = gelu_fast(a2.y);
        *(float2*)(&hs[2][k0]) = o;
        o.x = gelu_fast(a3.x); o.y = gelu_fast(a3.y);
        *(float2*)(&hs[3][k0]) = o;
    }
    __syncthreads();

    // ---- Stage C: logits = b2 + H @ w2 (k split over 8 groups) ------------
    {
        const int pq = t & 31;          // p-quad: p0 = pq*4
        const int p0 = pq * 4;
        const int kg = t >> 5;          // k-group 0..7, 64 k each
        float4 a0 = make_float4(0.f,0.f,0.f,0.f);
        float4 a1 = a0, a2 = a0, a3 = a0;
        const float4* __restrict__ w24 = (const float4*)(w2 + p0);
        #pragma unroll 8
        for (int i = 0; i < 64; ++i) {
            const int k = kg * 64 + i;
            const float4 w4 = w24[(size_t)k * 32];
            const float h0 = hs[0][k], h1 = hs[1][k];
            const float h2 = hs[2][k], h3 = hs[3][k];
            a0.x += h0*w4.x; a0.y += h0*w4.y; a0.z += h0*w4.z; a0.w += h0*w4.w;
            a1.x += h1*w4.x; a1.y += h1*w4.y; a1.z += h1*w4.z; a1.w += h1*w4.w;
            a2.x += h2*w4.x; a2.y += h2*w4.y; a2.z += h2*w4.z; a2.w += h2*w4.w;
            a3.x += h3*w4.x; a3.y += h3*w4.y; a3.z += h3*w4.z; a3.w += h3*w4.w;
        }
        ((float4*)par[kg][0])[pq] = a0;
        ((float4*)par[kg][1])[pq] = a1;
        ((float4*)par[kg][2])[pq] = a2;
        ((float4*)par[kg][3])[pq] = a3;
    }
    __syncthreads();

    // ---- Reduce + emit ----------------------------------------------------
    const int p  = t & 127;
    const int rh = t >> 7;              // this thread covers rows rh and rh+2
    float lg0 = b2[p], lg1 = lg0;
    #pragma unroll
    for (int kg = 0; kg < 8; ++kg) {
        lg0 += par[kg][rh][p];
        lg1 += par[kg][rh + 2][p];
    }

    if (mlp == 0) {
        float* __restrict__ dst = nadjT + (size_t)(b * NP + p) * NS + n0;
        dst[rh]     = lg0;
        dst[rh + 2] = lg1;
    } else {
        // Softmax over p (128 values = 2 waves per row): wave shfl reduce +
        // one LDS exchange between the wave pair.
        const int wid   = t >> 6;       // 0..3
        const int wpair = wid ^ 1;      // other wave of the same row
        float m0 = lg0, m1 = lg1;
        #pragma unroll
        for (int off = 32; off > 0; off >>= 1) {
            m0 = fmaxf(m0, __shfl_xor(m0, off));
            m1 = fmaxf(m1, __shfl_xor(m1, off));
        }
        if ((t & 63) == 0) { wred[wid][0] = m0; wred[wid][1] = m1; }
        __syncthreads();
        m0 = fmaxf(m0, wred[wpair][0]);
        m1 = fmaxf(m1, wred[wpair][1]);

        const float e0 = expf(lg0 - m0), e1 = expf(lg1 - m1);
        float s0 = e0, s1 = e1;
        #pragma unroll
        for (int off = 32; off > 0; off >>= 1) {
            s0 += __shfl_xor(s0, off);
            s1 += __shfl_xor(s1, off);
        }
        __syncthreads();   // all reads of wred (max) done before overwrite
        if ((t & 63) == 0) { wred[wid][0] = s0; wred[wid][1] = s1; }
        __syncthreads();
        s0 += wred[wpair][0];
        s1 += wred[wpair][1];

        attn[(size_t)(g0 + rh) * NP + p]     = e0 / s0;
        attn[(size_t)(g0 + rh + 2) * NP + p] = e1 / s1;
    }
}

// ---------------------------------------------------------------------------
// K_fold: fused (node_w/node_h einsums + tf MLP). grid = 4*128 = 512 blocks.
// Weight/adjacency operands read via wave-uniform indices -> scalar loads;
// inner loop is v_fmac with SGPR operands. No LDS. Fast gelu (48/thread).
// ---------------------------------------------------------------------------
__global__ __launch_bounds__(256) void k_fold(
    const float* __restrict__ nadjT, const float* __restrict__ ti,
    const float* __restrict__ w1p,   // precomputed [24][48] (k_mlp block 288)
    const float* __restrict__ b1, const float* __restrict__ w2,
    const float* __restrict__ b2, float* __restrict__ tf)
{
    const int b = blockIdx.x >> 7;
    const int p = blockIdx.x & 127;
    const int t = threadIdx.x;

    const float* __restrict__ an = nadjT + (size_t)(b * NP + p) * NS; // uniform
    const int d = t;
    const float* __restrict__ tb = ti + (size_t)b * NS * DIM + d;

    float v[24];
    #pragma unroll
    for (int m = 0; m < 24; ++m) v[m] = 0.f;
    #pragma unroll
    for (int y = 0; y < 12; ++y) {
        #pragma unroll
        for (int x = 0; x < 12; ++x) {
            const int n = y * 12 + x;
            const float tv = tb[n * DIM];   // vector, lane-coalesced
            const float a  = an[n];         // uniform -> scalar load
            v[y]      += a * tv;   // node_w: m=y, j=x
            v[12 + x] += a * tv;   // node_h: m=12+x, j=y
        }
    }
    const float c = 0.40824829046386301637f;  // 2/sqrt(24)
    #pragma unroll
    for (int m = 0; m < 24; ++m) v[m] *= c;

    float acc = b2[0];
    for (int k = 0; k < 48; ++k) {
        float tt = b1[k];                       // uniform
        #pragma unroll
        for (int m = 0; m < 24; ++m) tt += v[m] * w1p[m * 48 + k];  // uniform
        acc += gelu_fast(tt) * w2[k];           // uniform
    }
    tf[(size_t)(b * NP + p) * DIM + d] = acc;
}

// ---------------------------------------------------------------------------
// K_final (merged): one block per output row g. row[d] = ti[g][d] +
// sum_p attn[g][p]*tf[b,p,d]; broadcast-scatter to out[b,h,w,:]. grid = 576.
// ---------------------------------------------------------------------------
__global__ __launch_bounds__(256) void k_final(
    const float* __restrict__ attn, const float* __restrict__ tf,
    const float* __restrict__ ti, float4* __restrict__ out)
{
    const int g = blockIdx.x;
    const int b = g / NS;
    const int n = g % NS;
    const int t = threadIdx.x;
    const int dq = t & 63;
    const int pg = t >> 6;

    __shared__ float  at[NP];
    __shared__ float4 par4[4][64];
    __shared__ float4 rowf[64];

    if (t < NP) at[t] = attn[(size_t)g * NP + t];
    __syncthreads();

    const float4* __restrict__ tp = (const float4*)tf + (size_t)b * NP * 64 + dq;
    float4 acc = make_float4(0.f, 0.f, 0.f, 0.f);
    #pragma unroll 16
    for (int i = 0; i < 32; ++i) {
        const int pp = pg * 32 + i;
        const float  a  = at[pp];
        const float4 tv = tp[(size_t)pp * 64];
        acc.x += a * tv.x; acc.y += a * tv.y;
        acc.z += a * tv.z; acc.w += a * tv.w;
    }
    par4[pg][dq] = acc;
    __syncthreads();

    if (t < 64) {
        float4 s = par4[0][t];
        const float4 s1 = par4[1][t], s2 = par4[2][t], s3 = par4[3][t];
        const float4 tiv = ((const float4*)ti)[(size_t)g * 64 + t];
        s.x += s1.x + s2.x + s3.x + tiv.x;
        s.y += s1.y + s2.y + s3.y + tiv.y;
        s.z += s1.z + s2.z + s3.z + tiv.z;
        s.w += s1.w + s2.w + s3.w + tiv.w;
        rowf[t] = s;
    }
    __syncthreads();

    // scatter: src(h,w) = (h/10)*12 + (3w)/40 == n  <=>  h in [10y,10y+10),
    // w in [ceil(40x/3), ceil(40(x+1)/3)) where n = y*12+x.
    const int y = n / 12, x = n % 12;
    const int w_lo = (40 * x + 2) / 3;
    const int w_hi = (40 * x + 42) / 3;
    const float4 val = rowf[dq];
    const int h0 = 10 * y;
    for (int h = h0; h < h0 + 10; ++h) {
        float4* __restrict__ orow = out + (size_t)((b * H_OUT + h) * W_OUT) * 64 + dq;
        for (int w = w_lo + pg; w < w_hi; w += 4) {
            orow[(size_t)w * 64] = val;
        }
    }
}

extern "C" void kernel_launch(void* const* d_in, const int* in_sizes, int n_in,
                              void* d_out, int out_size, void* d_ws, size_t ws_size,
                              hipStream_t stream) {
    (void)in_sizes; (void)n_in; (void)out_size; (void)ws_size;
    const float* token_init  = (const float*)d_in[0];  // [4,144,256]
    const float* point_token = (const float*)d_in[1];  // [4,128,256]
    const float* nr_w1 = (const float*)d_in[2];
    const float* nr_b1 = (const float*)d_in[3];
    const float* nr_w2 = (const float*)d_in[4];
    const float* nr_b2 = (const float*)d_in[5];
    const float* na_w1 = (const float*)d_in[6];
    const float* na_b1 = (const float*)d_in[7];
    const float* na_w2 = (const float*)d_in[8];
    const float* na_b2 = (const float*)d_in[9];
    const float* tf_w1 = (const float*)d_in[10];
    const float* tf_b1 = (const float*)d_in[11];
    const float* tf_w2 = (const float*)d_in[12];
    const float* tf_b2 = (const float*)d_in[13];

    float* out = (float*)d_out;
    float* ws  = (float*)d_ws;
    float* nadjT = ws;                  //  73,728 f  [b*NP+p][n]
    float* attn  = nadjT + NROW * NP;   //  73,728 f
    float* tf    = attn + NROW * NP;    // 131,072 f
    float* w1pg  = tf + B * NP * DIM;   //   1,152 f  [24][48]

    k_mlp<<<289, 256, 0, stream>>>(token_init, point_token,
                                   nr_w1, nr_b1, nr_w2, nr_b2,
                                   na_w1, na_b1, na_w2, na_b2,
                                   tf_w1, nadjT, attn, w1pg);
    k_fold<<<B * NP, 256, 0, stream>>>(nadjT, token_init, w1pg,
                                       tf_b1, tf_w2, tf_b2, tf);
    k_final<<<NROW, 256, 0, stream>>>(attn, tf, token_init, (float4*)out);
}